// Round 5
// baseline (84.215 us; speedup 1.0000x reference)
//
#include <hip/hip_runtime.h>
#include <math.h>

#define NCOL  6000
#define NV    1500      // float4 count per row
#define BLOCK 1024
#define NWAVE 16        // BLOCK/64
#define SLOTS 1536      // padded so the partial tail wave's LDS writes stay in-bounds

__device__ __forceinline__ void gload16(const void* g, void* l) {
    __builtin_amdgcn_global_load_lds(
        (const __attribute__((address_space(1))) void*)g,
        (__attribute__((address_space(3))) void*)l, 16, 0, 0);
}

__device__ __forceinline__ float wave_max_f(float v) {
    #pragma unroll
    for (int off = 32; off > 0; off >>= 1) v = fmaxf(v, __shfl_xor(v, off, 64));
    return v;
}
__device__ __forceinline__ float wave_min_f(float v) {
    #pragma unroll
    for (int off = 32; off > 0; off >>= 1) v = fminf(v, __shfl_xor(v, off, 64));
    return v;
}
__device__ __forceinline__ int wave_sum_i(int v) {
    #pragma unroll
    for (int off = 32; off > 0; off >>= 1) v += __shfl_xor(v, off, 64);
    return v;
}
__device__ __forceinline__ double wave_sum_d(double v) {
    #pragma unroll
    for (int off = 32; off > 0; off >>= 1) v += __shfl_xor(v, off, 64);
    return v;
}

__global__ __launch_bounds__(BLOCK, 8) void row_kl_kernel(
    const float* __restrict__ yp, const float* __restrict__ yt,
    const int* __restrict__ mk, float* __restrict__ rowkl)
{
    __shared__ float4 sp4s[SLOTS];     // y_pred staging (raw)
    __shared__ float4 st4s[SLOTS];     // y_true staging (raw)
    __shared__ int4   sm4s[SLOTS];     // masks staging (raw)
    __shared__ float  swf[3][NWAVE];
    __shared__ int    swi[NWAVE];
    __shared__ double swd[3][NWAVE];

    const int row  = blockIdx.x;
    const int tid  = threadIdx.x;
    const int lane = tid & 63;
    const int wid  = tid >> 6;

    const float4* yp4 = reinterpret_cast<const float4*>(yp) + (size_t)row * NV;
    const float4* yt4 = reinterpret_cast<const float4*>(yt) + (size_t)row * NV;
    const int4*   mk4 = reinterpret_cast<const int4*>(mk) + (size_t)row * NV;

    // ---- async global -> LDS staging (no VGPR payload; back-to-back issue) ----
    // batch 0: slots [0,1024), all valid (1024 < 1500)
    {
        const int base = wid * 64;                 // wave-uniform LDS slot base
        gload16(yp4 + tid, (char*)sp4s + (size_t)base * 16);
        gload16(yt4 + tid, (char*)st4s + (size_t)base * 16);
        gload16(mk4 + tid, (char*)sm4s + (size_t)base * 16);
    }
    // batch 1: slots [1024, 2048); only waves whose base slot < NV issue
    {
        const int base = 1024 + wid * 64;          // wave-uniform
        if (base < NV) {
            const int v1 = 1024 + tid;
            const int c1 = (v1 < NV) ? v1 : (NV - 1);   // clamp per-lane global addr
            gload16(yp4 + c1, (char*)sp4s + (size_t)base * 16);
            gload16(yt4 + c1, (char*)st4s + (size_t)base * 16);
            gload16(mk4 + c1, (char*)sm4s + (size_t)base * 16);
        }
    }
    // wait for this wave's own DMA (own slots only -> no __syncthreads needed)
    asm volatile("s_waitcnt vmcnt(0)" ::: "memory");

    // ---- phase 1: read own slots from LDS, mask into registers, row stats ----
    float xr[8], tr[8];
    float maxp = -1e30f, tmin = 1e30f, tmax = -1e30f;
    int cnt = 0;

    #pragma unroll
    for (int b = 0; b < 2; ++b) {
        const int v  = b * 1024 + tid;
        const int vc = (v < NV) ? v : 0;
        float4 xq = sp4s[vc];
        float4 tq = st4s[vc];
        int4   mq = sm4s[vc];
        if (v >= NV) { mq.x = 0; mq.y = 0; mq.z = 0; mq.w = 0; }
        {
            bool m = mq.x > 0;
            float x = m ? xq.x : -1e30f; float t = m ? tq.x : -1e30f;
            tmin = fminf(tmin, m ? tq.x : 1e30f);
            xr[4*b+0] = x; tr[4*b+0] = t;
            maxp = fmaxf(maxp, x); tmax = fmaxf(tmax, t); cnt += m;
        }
        {
            bool m = mq.y > 0;
            float x = m ? xq.y : -1e30f; float t = m ? tq.y : -1e30f;
            tmin = fminf(tmin, m ? tq.y : 1e30f);
            xr[4*b+1] = x; tr[4*b+1] = t;
            maxp = fmaxf(maxp, x); tmax = fmaxf(tmax, t); cnt += m;
        }
        {
            bool m = mq.z > 0;
            float x = m ? xq.z : -1e30f; float t = m ? tq.z : -1e30f;
            tmin = fminf(tmin, m ? tq.z : 1e30f);
            xr[4*b+2] = x; tr[4*b+2] = t;
            maxp = fmaxf(maxp, x); tmax = fmaxf(tmax, t); cnt += m;
        }
        {
            bool m = mq.w > 0;
            float x = m ? xq.w : -1e30f; float t = m ? tq.w : -1e30f;
            tmin = fminf(tmin, m ? tq.w : 1e30f);
            xr[4*b+3] = x; tr[4*b+3] = t;
            maxp = fmaxf(maxp, x); tmax = fmaxf(tmax, t); cnt += m;
        }
    }

    // ---- block-wide reduce of row stats ----
    maxp = wave_max_f(maxp);
    tmin = wave_min_f(tmin);
    tmax = wave_max_f(tmax);
    cnt  = wave_sum_i(cnt);
    if (lane == 0) { swf[0][wid] = maxp; swf[1][wid] = tmin; swf[2][wid] = tmax; swi[wid] = cnt; }
    __syncthreads();
    maxp = -1e30f; tmin = 1e30f; tmax = -1e30f; cnt = 0;
    #pragma unroll
    for (int j = 0; j < NWAVE; ++j) {
        maxp = fmaxf(maxp, swf[0][j]);
        tmin = fminf(tmin, swf[1][j]);
        tmax = fmaxf(tmax, swf[2][j]);
        cnt += swi[j];
    }

    const float rng   = tmax - tmin;
    const bool scaled = rng > 0.0f;
    const float inv_s = 1.0f / (rng + 1e-12f);
    const float maxz  = scaled ? rng * inv_s : tmax;

    // ---- phase 2: everything from registers ----
    // Zp = sum exp(x-maxp); S1 = sum exp(z-maxz); S2 = sum exp(z-maxz)*(z-x)
    double Zp = 0.0, S1 = 0.0, S2 = 0.0;
    #pragma unroll
    for (int e = 0; e < 8; ++e) {
        float x = xr[e];
        float t = tr[e];
        float ep = __expf(x - maxp);             // masked -> 0
        float z  = scaled ? (t - tmin) * inv_s : t;
        z = fmaxf(z, -1e30f);                    // keep finite so e1*(z-x)=0
        float e1 = __expf(z - maxz);             // masked -> 0
        Zp += (double)ep;
        S1 += (double)e1;
        S2 += (double)e1 * (double)(z - x);
    }
    Zp = wave_sum_d(Zp);
    S1 = wave_sum_d(S1);
    S2 = wave_sum_d(S2);
    if (lane == 0) { swd[0][wid] = Zp; swd[1][wid] = S1; swd[2][wid] = S2; }
    __syncthreads();
    if (tid == 0) {
        double zp = 0.0, s1 = 0.0, s2 = 0.0;
        #pragma unroll
        for (int j = 0; j < NWAVE; ++j) { zp += swd[0][j]; s1 += swd[1][j]; s2 += swd[2][j]; }
        float val = 0.0f;
        if (cnt >= 2) {
            // kl_sum = S2/S1 + (maxp + log Zp - maxz - log S1)
            double kl = s2 / s1 + ((double)maxp + log(zp) - (double)maxz - log(s1));
            double v  = kl / (double)cnt;
            if (isfinite(v)) val = (float)v;
        }
        rowkl[row] = val;
    }
}

__global__ __launch_bounds__(256) void final_reduce_kernel(
    const float* __restrict__ rowkl, float* __restrict__ out, int nrows)
{
    __shared__ double swd[4];
    const int tid  = threadIdx.x;
    const int lane = tid & 63;
    const int wid  = tid >> 6;
    double acc = 0.0;
    for (int i = tid; i < nrows; i += 256) acc += (double)rowkl[i];
    acc = wave_sum_d(acc);
    if (lane == 0) swd[wid] = acc;
    __syncthreads();
    if (tid == 0) {
        double tot = 0.0;
        #pragma unroll
        for (int j = 0; j < 4; ++j) tot += swd[j];
        out[0] = (float)(tot / (double)nrows);
    }
}

extern "C" void kernel_launch(void* const* d_in, const int* in_sizes, int n_in,
                              void* d_out, int out_size, void* d_ws, size_t ws_size,
                              hipStream_t stream) {
    const float* y_pred = (const float*)d_in[0];
    const float* y_true = (const float*)d_in[1];
    const int*   masks  = (const int*)d_in[2];
    float* out = (float*)d_out;
    float* rowkl = (float*)d_ws;

    const int B = in_sizes[0] / NCOL;   // 4096

    row_kl_kernel<<<B, BLOCK, 0, stream>>>(y_pred, y_true, masks, rowkl);
    final_reduce_kernel<<<1, 256, 0, stream>>>(rowkl, out, B);
}

// Round 6
// 56.832 us; speedup vs baseline: 1.4818x; 1.4818x over previous
//
#include <hip/hip_runtime.h>
#include <math.h>

#define NCOL  6000
#define NV    1500      // float4 count per row
#define BLOCK 512
#define NWAVE 8         // BLOCK/64
#define EPT   3         // float4 per thread; 512*3*4 = 6144 >= 6000

__device__ __forceinline__ float wave_max_f(float v) {
    #pragma unroll
    for (int off = 32; off > 0; off >>= 1) v = fmaxf(v, __shfl_xor(v, off, 64));
    return v;
}
__device__ __forceinline__ float wave_min_f(float v) {
    #pragma unroll
    for (int off = 32; off > 0; off >>= 1) v = fminf(v, __shfl_xor(v, off, 64));
    return v;
}
__device__ __forceinline__ int wave_sum_i(int v) {
    #pragma unroll
    for (int off = 32; off > 0; off >>= 1) v += __shfl_xor(v, off, 64);
    return v;
}
__device__ __forceinline__ double wave_sum_d(double v) {
    #pragma unroll
    for (int off = 32; off > 0; off >>= 1) v += __shfl_xor(v, off, 64);
    return v;
}

// min waves/EU = 4 -> 128-VGPR budget: enough to keep all 9 loads in flight.
__global__ __launch_bounds__(BLOCK, 4) void row_kl_kernel(
    const float* __restrict__ yp, const float* __restrict__ yt,
    const int* __restrict__ mk, float* __restrict__ rowkl)
{
    __shared__ float  swf[3][NWAVE];
    __shared__ int    swi[NWAVE];
    __shared__ double swd[3][NWAVE];

    const int row  = blockIdx.x;
    const int tid  = threadIdx.x;
    const int lane = tid & 63;
    const int wid  = tid >> 6;

    const float4* yp4 = reinterpret_cast<const float4*>(yp) + (size_t)row * NV;
    const float4* yt4 = reinterpret_cast<const float4*>(yt) + (size_t)row * NV;
    const int4*   mk4 = reinterpret_cast<const int4*>(mk) + (size_t)row * NV;

    // ---- batch-issue all 9 loads (independent; keep in flight) ----
    const int v2 = tid + 2 * BLOCK;
    const int vc2 = (v2 < NV) ? v2 : 0;       // clamp OOB tail
    float4 xp[EPT], xt[EPT];
    int4   mm[EPT];
    xp[0] = yp4[tid];
    xp[1] = yp4[tid + BLOCK];
    xp[2] = yp4[vc2];
    xt[0] = yt4[tid];
    xt[1] = yt4[tid + BLOCK];
    xt[2] = yt4[vc2];
    mm[0] = mk4[tid];
    mm[1] = mk4[tid + BLOCK];
    mm[2] = mk4[vc2];
    if (v2 >= NV) { mm[2].x = 0; mm[2].y = 0; mm[2].z = 0; mm[2].w = 0; }

    // ---- phase 1: mask in place (xp/xt become masked x/t), row stats ----
    float maxp = -1e30f, tmin = 1e30f, tmax = -1e30f;
    int cnt = 0;
    #pragma unroll
    for (int j = 0; j < EPT; ++j) {
        {
            bool m = mm[j].x > 0;
            float x = m ? xp[j].x : -1e30f;
            float t = m ? xt[j].x : -1e30f;
            tmin = fminf(tmin, m ? xt[j].x : 1e30f);
            xp[j].x = x; xt[j].x = t;
            maxp = fmaxf(maxp, x); tmax = fmaxf(tmax, t); cnt += m;
        }
        {
            bool m = mm[j].y > 0;
            float x = m ? xp[j].y : -1e30f;
            float t = m ? xt[j].y : -1e30f;
            tmin = fminf(tmin, m ? xt[j].y : 1e30f);
            xp[j].y = x; xt[j].y = t;
            maxp = fmaxf(maxp, x); tmax = fmaxf(tmax, t); cnt += m;
        }
        {
            bool m = mm[j].z > 0;
            float x = m ? xp[j].z : -1e30f;
            float t = m ? xt[j].z : -1e30f;
            tmin = fminf(tmin, m ? xt[j].z : 1e30f);
            xp[j].z = x; xt[j].z = t;
            maxp = fmaxf(maxp, x); tmax = fmaxf(tmax, t); cnt += m;
        }
        {
            bool m = mm[j].w > 0;
            float x = m ? xp[j].w : -1e30f;
            float t = m ? xt[j].w : -1e30f;
            tmin = fminf(tmin, m ? xt[j].w : 1e30f);
            xp[j].w = x; xt[j].w = t;
            maxp = fmaxf(maxp, x); tmax = fmaxf(tmax, t); cnt += m;
        }
    }

    // ---- block-wide reduce of row stats ----
    maxp = wave_max_f(maxp);
    tmin = wave_min_f(tmin);
    tmax = wave_max_f(tmax);
    cnt  = wave_sum_i(cnt);
    if (lane == 0) { swf[0][wid] = maxp; swf[1][wid] = tmin; swf[2][wid] = tmax; swi[wid] = cnt; }
    __syncthreads();
    maxp = -1e30f; tmin = 1e30f; tmax = -1e30f; cnt = 0;
    #pragma unroll
    for (int j = 0; j < NWAVE; ++j) {
        maxp = fmaxf(maxp, swf[0][j]);
        tmin = fminf(tmin, swf[1][j]);
        tmax = fmaxf(tmax, swf[2][j]);
        cnt += swi[j];
    }

    const float rng   = tmax - tmin;
    const bool scaled = rng > 0.0f;
    const float inv_s = 1.0f / (rng + 1e-12f);
    const float maxz  = scaled ? rng * inv_s : tmax;

    // ---- phase 2: everything from registers ----
    // Zp = sum exp(x-maxp); S1 = sum exp(z-maxz); S2 = sum exp(z-maxz)*(z-x)
    double Zp = 0.0, S1 = 0.0, S2 = 0.0;
    #pragma unroll
    for (int j = 0; j < EPT; ++j) {
        #pragma unroll
        for (int c = 0; c < 4; ++c) {
            float x = (c == 0) ? xp[j].x : (c == 1) ? xp[j].y : (c == 2) ? xp[j].z : xp[j].w;
            float t = (c == 0) ? xt[j].x : (c == 1) ? xt[j].y : (c == 2) ? xt[j].z : xt[j].w;
            float ep = __expf(x - maxp);             // masked -> 0
            float z  = scaled ? (t - tmin) * inv_s : t;
            z = fmaxf(z, -1e30f);                    // keep finite so e1*(z-x)=0
            float e1 = __expf(z - maxz);             // masked -> 0
            Zp += (double)ep;
            S1 += (double)e1;
            S2 += (double)e1 * (double)(z - x);
        }
    }
    Zp = wave_sum_d(Zp);
    S1 = wave_sum_d(S1);
    S2 = wave_sum_d(S2);
    if (lane == 0) { swd[0][wid] = Zp; swd[1][wid] = S1; swd[2][wid] = S2; }
    __syncthreads();
    if (tid == 0) {
        double zp = 0.0, s1 = 0.0, s2 = 0.0;
        #pragma unroll
        for (int j = 0; j < NWAVE; ++j) { zp += swd[0][j]; s1 += swd[1][j]; s2 += swd[2][j]; }
        float val = 0.0f;
        if (cnt >= 2) {
            // kl_sum = S2/S1 + (maxp + log Zp - maxz - log S1)
            double kl = s2 / s1 + ((double)maxp + log(zp) - (double)maxz - log(s1));
            double v  = kl / (double)cnt;
            if (isfinite(v)) val = (float)v;
        }
        rowkl[row] = val;
    }
}

__global__ __launch_bounds__(256) void final_reduce_kernel(
    const float* __restrict__ rowkl, float* __restrict__ out, int nrows)
{
    __shared__ double swd[4];
    const int tid  = threadIdx.x;
    const int lane = tid & 63;
    const int wid  = tid >> 6;
    double acc = 0.0;
    for (int i = tid; i < nrows; i += 256) acc += (double)rowkl[i];
    acc = wave_sum_d(acc);
    if (lane == 0) swd[wid] = acc;
    __syncthreads();
    if (tid == 0) {
        double tot = 0.0;
        #pragma unroll
        for (int j = 0; j < 4; ++j) tot += swd[j];
        out[0] = (float)(tot / (double)nrows);
    }
}

extern "C" void kernel_launch(void* const* d_in, const int* in_sizes, int n_in,
                              void* d_out, int out_size, void* d_ws, size_t ws_size,
                              hipStream_t stream) {
    const float* y_pred = (const float*)d_in[0];
    const float* y_true = (const float*)d_in[1];
    const int*   masks  = (const int*)d_in[2];
    float* out = (float*)d_out;
    float* rowkl = (float*)d_ws;

    const int B = in_sizes[0] / NCOL;   // 4096

    row_kl_kernel<<<B, BLOCK, 0, stream>>>(y_pred, y_true, masks, rowkl);
    final_reduce_kernel<<<1, 256, 0, stream>>>(rowkl, out, B);
}